// Round 1
// baseline (617.401 us; speedup 1.0000x reference)
//
#include <hip/hip_runtime.h>
#include <cstddef>

// Problem constants (from reference): B=8192, T=512, I=4, H=32, O=4
constexpr int kB = 8192;
constexpr int kT = 512;
constexpr int kI = 4;
constexpr int kH = 32;
constexpr int kO = 4;

// tanh(x) = 1 - 2/(e^{2x}+1), via v_exp_f32 (base-2) + v_rcp_f32.
// Saturates correctly at +/-inf; rel err ~1e-7 — far below harness threshold.
__device__ __forceinline__ float fast_tanh(float x) {
    float e = __builtin_amdgcn_exp2f(x * 2.8853900817779268f);  // e^{2x}
    return 1.0f - 2.0f * __builtin_amdgcn_rcpf(e + 1.0f);
}

// One 32-lane group per batch element; 2 groups per wave, 8 per 256-thr block.
// Lane j holds weight ROW j of each matrix in registers; h0/h1 full vectors in
// registers (statically indexed); per-step LDS stage redistributes the 32 new
// h values within the group (wave-synchronous, no block barriers needed).
__global__ __launch_bounds__(256, 2) void rnn2_fwd(
    const float* __restrict__ X,
    const float* __restrict__ W_ih0, const float* __restrict__ W_hh0,
    const float* __restrict__ b_ih0, const float* __restrict__ b_hh0,
    const float* __restrict__ W_ih1, const float* __restrict__ W_hh1,
    const float* __restrict__ b_ih1, const float* __restrict__ b_hh1,
    const float* __restrict__ W_ll, const float* __restrict__ b_ll,
    float* __restrict__ out)
{
    const int tid = threadIdx.x;
    const int j   = tid & 31;        // unit index within group
    const int grp = tid >> 5;        // group within block (0..7)
    const int b   = blockIdx.x * 8 + grp;  // batch element
    const int oo  = j >> 3;          // which output this lane helps with
    const int cc  = j & 7;           // 4-wide chunk of the h1 dot product

    __shared__ __align__(16) float stage[8][kH];   // per-group h exchange

    // ---- weight rows into registers (one-time) ----
    float wih0[kI], whh0[kH], wih1[kH], whh1[kH];
    {
        float4 v = *(const float4*)(W_ih0 + j * kI);
        wih0[0] = v.x; wih0[1] = v.y; wih0[2] = v.z; wih0[3] = v.w;
    }
#pragma unroll
    for (int q = 0; q < kH / 4; ++q) {
        float4 v = *(const float4*)(W_hh0 + j * kH + q * 4);
        whh0[q*4+0] = v.x; whh0[q*4+1] = v.y; whh0[q*4+2] = v.z; whh0[q*4+3] = v.w;
    }
#pragma unroll
    for (int q = 0; q < kH / 4; ++q) {
        float4 v = *(const float4*)(W_ih1 + j * kH + q * 4);
        wih1[q*4+0] = v.x; wih1[q*4+1] = v.y; wih1[q*4+2] = v.z; wih1[q*4+3] = v.w;
    }
#pragma unroll
    for (int q = 0; q < kH / 4; ++q) {
        float4 v = *(const float4*)(W_hh1 + j * kH + q * 4);
        whh1[q*4+0] = v.x; whh1[q*4+1] = v.y; whh1[q*4+2] = v.z; whh1[q*4+3] = v.w;
    }
    const float4 wv = *(const float4*)(W_ll + oo * kH + cc * 4);  // W_ll chunk
    const float b0  = b_ih0[j] + b_hh0[j];
    const float b1  = b_ih1[j] + b_hh1[j];
    const float bll = b_ll[oo];

    // ---- recurrent state ----
    float h0[kH], h1[kH];
#pragma unroll
    for (int k = 0; k < kH; ++k) { h0[k] = 0.0f; h1[k] = 0.0f; }

    const float* xp = X   + (size_t)b * (kT * kI);
    float*       op = out + (size_t)b * (kT * kO);

    float4 xv = *(const float4*)(xp);   // x_0

    for (int t = 0; t < kT; ++t) {
        // prefetch next step's x (guarded; re-reads last element at t=T-1)
        const int tn = (t + 1 < kT) ? (t + 1) : (kT - 1);
        float4 xnext = *(const float4*)(xp + tn * 4);

        // ---- layer 0: h0n_j = tanh(Wih0[j]·x + Whh0[j]·h0 + b0) ----
        float acc0 = b0;
        acc0 = fmaf(wih0[0], xv.x, acc0);
        acc0 = fmaf(wih0[1], xv.y, acc0);
        acc0 = fmaf(wih0[2], xv.z, acc0);
        acc0 = fmaf(wih0[3], xv.w, acc0);
#pragma unroll
        for (int k = 0; k < kH; ++k) acc0 = fmaf(whh0[k], h0[k], acc0);
        const float h0n = fast_tanh(acc0);

        // ---- redistribute h0 within group (wave-synchronous) ----
        __builtin_amdgcn_wave_barrier();   // prior-iter reads before overwrite
        stage[grp][j] = h0n;
        __builtin_amdgcn_wave_barrier();
#pragma unroll
        for (int q = 0; q < kH / 4; ++q) {
            float4 v = *(const float4*)&stage[grp][q * 4];
            h0[q*4+0] = v.x; h0[q*4+1] = v.y; h0[q*4+2] = v.z; h0[q*4+3] = v.w;
        }
        __builtin_amdgcn_wave_barrier();   // reads before h1 overwrite

        // ---- layer 1: h1n_j = tanh(Wih1[j]·h0n + Whh1[j]·h1 + b1) ----
        float acc1 = b1;
#pragma unroll
        for (int k = 0; k < kH; ++k) acc1 = fmaf(wih1[k], h0[k], acc1);
#pragma unroll
        for (int k = 0; k < kH; ++k) acc1 = fmaf(whh1[k], h1[k], acc1);
        const float h1n = fast_tanh(acc1);

        // ---- redistribute h1 ----
        stage[grp][j] = h1n;
        __builtin_amdgcn_wave_barrier();
#pragma unroll
        for (int q = 0; q < kH / 4; ++q) {
            float4 v = *(const float4*)&stage[grp][q * 4];
            h1[q*4+0] = v.x; h1[q*4+1] = v.y; h1[q*4+2] = v.z; h1[q*4+3] = v.w;
        }

        // ---- linear head: out[b][t*4+oo] = W_ll[oo]·h1 + b_ll[oo] ----
        // lane (oo,cc) does a 4-wide chunk, butterfly-reduce over the 8 chunks
        const float4 hv = *(const float4*)&stage[grp][cc * 4];
        float p = 0.0f;
        p = fmaf(wv.x, hv.x, p);
        p = fmaf(wv.y, hv.y, p);
        p = fmaf(wv.z, hv.z, p);
        p = fmaf(wv.w, hv.w, p);
        p += __shfl_xor(p, 1);
        p += __shfl_xor(p, 2);
        p += __shfl_xor(p, 4);
        if (cc == 0) op[t * kO + oo] = p + bll;

        xv = xnext;
    }
}

extern "C" void kernel_launch(void* const* d_in, const int* in_sizes, int n_in,
                              void* d_out, int out_size, void* d_ws, size_t ws_size,
                              hipStream_t stream) {
    const float* X     = (const float*)d_in[0];
    const float* W_ih0 = (const float*)d_in[1];
    const float* W_hh0 = (const float*)d_in[2];
    const float* b_ih0 = (const float*)d_in[3];
    const float* b_hh0 = (const float*)d_in[4];
    const float* W_ih1 = (const float*)d_in[5];
    const float* W_hh1 = (const float*)d_in[6];
    const float* b_ih1 = (const float*)d_in[7];
    const float* b_hh1 = (const float*)d_in[8];
    const float* W_ll  = (const float*)d_in[9];
    const float* b_ll  = (const float*)d_in[10];
    float* out = (float*)d_out;

    dim3 grid(kB / 8);   // 8 batch elements per 256-thread block
    dim3 block(256);
    rnn2_fwd<<<grid, block, 0, stream>>>(X, W_ih0, W_hh0, b_ih0, b_hh0,
                                         W_ih1, W_hh1, b_ih1, b_hh1,
                                         W_ll, b_ll, out);
}

// Round 2
// 250.422 us; speedup vs baseline: 2.4654x; 2.4654x over previous
//
#include <hip/hip_runtime.h>
#include <cstddef>
#include <cstdint>

// B=8192, T=512, I=4, H=32, O=4 — 2-layer tanh RNN + linear head, fp32 I/O.
constexpr int kB = 8192, kT = 512, kI = 4, kH = 32, kO = 4;

typedef _Float16 f16x8 __attribute__((ext_vector_type(8)));
typedef _Float16 f16x2 __attribute__((ext_vector_type(2)));
typedef float    f32x4 __attribute__((ext_vector_type(4)));

#define MFMA(a, b, c) __builtin_amdgcn_mfma_f32_16x16x32_f16((a), (b), (c), 0, 0, 0)

__device__ __forceinline__ float fast_tanh(float x) {
    // tanh(x) = 1 - 2/(e^{2x}+1); exp2-based, saturates correctly, rel err ~1e-6
    float e = __builtin_amdgcn_exp2f(x * 2.8853900817779268f);
    return 1.0f - 2.0f * __builtin_amdgcn_rcpf(e + 1.0f);
}

__device__ __forceinline__ float4 ld4(const float* p) { return *(const float4*)p; }

// Build an 8×f16 A/B fragment from two float4s: elems 0-3 = k-half {4g..4g+3},
// elems 4-7 = k-half {16+4g..16+4g+3} (RNE conversion; used once for weights).
__device__ __forceinline__ f16x8 pack_frag(float4 lo, float4 hi) {
    f16x8 r;
    r[0] = (_Float16)lo.x; r[1] = (_Float16)lo.y;
    r[2] = (_Float16)lo.z; r[3] = (_Float16)lo.w;
    r[4] = (_Float16)hi.x; r[5] = (_Float16)hi.y;
    r[6] = (_Float16)hi.z; r[7] = (_Float16)hi.w;
    return r;
}

// State pack: D-tile0 regs (rows 4g..4g+3) -> B k-slots {4g+j}; D-tile1 regs
// (rows 16+4g..) -> k-slots {16+4g+j}. Pure per-lane: 4× v_cvt_pkrtz, no shuffles.
__device__ __forceinline__ f16x8 pack_state(f32x4 a, f32x4 b) {
    union { f16x8 v; uint32_t u[4]; } r;
    r.u[0] = __builtin_bit_cast(uint32_t, __builtin_amdgcn_cvt_pkrtz(a[0], a[1]));
    r.u[1] = __builtin_bit_cast(uint32_t, __builtin_amdgcn_cvt_pkrtz(a[2], a[3]));
    r.u[2] = __builtin_bit_cast(uint32_t, __builtin_amdgcn_cvt_pkrtz(b[0], b[1]));
    r.u[3] = __builtin_bit_cast(uint32_t, __builtin_amdgcn_cvt_pkrtz(b[2], b[3]));
    return r.v;
}

// One wave per 16-batch tile. State kept transposed (H^T) so the MFMA D layout
// feeds the next step's B operand directly (zero cross-lane traffic per step).
__global__ __launch_bounds__(64, 1) void rnn2_mfma(
    const float* __restrict__ X,
    const float* __restrict__ W_ih0, const float* __restrict__ W_hh0,
    const float* __restrict__ b_ih0, const float* __restrict__ b_hh0,
    const float* __restrict__ W_ih1, const float* __restrict__ W_hh1,
    const float* __restrict__ b_ih1, const float* __restrict__ b_hh1,
    const float* __restrict__ W_ll, const float* __restrict__ b_ll,
    float* __restrict__ out)
{
    const int  l  = threadIdx.x;      // 0..63
    const int  c  = l & 15;           // batch col within tile / A row m
    const int  g  = l >> 4;           // k-group
    const bool g0 = (g == 0);
    const int  b  = blockIdx.x * 16 + c;   // this lane's batch element
    const int  k0 = 4 * g;                 // k-half0 base (half1 = 16+k0)

    const float4 z4 = make_float4(0.f, 0.f, 0.f, 0.f);

    // ---- weight A-fragments (static, in registers) ----
    const float* wp;
    wp = W_hh0 + c * kH;
    const f16x8 Ahh0_0 = pack_frag(ld4(wp + k0), ld4(wp + 16 + k0));
    wp = W_hh0 + (c + 16) * kH;
    const f16x8 Ahh0_1 = pack_frag(ld4(wp + k0), ld4(wp + 16 + k0));

    // W_ih0 is [32][4]: only k<4 live -> lane-group 0, k-half0; all else zero.
    const f16x8 Aih0_0 = pack_frag(g0 ? ld4(W_ih0 + c * kI) : z4, z4);
    const f16x8 Aih0_1 = pack_frag(g0 ? ld4(W_ih0 + (c + 16) * kI) : z4, z4);

    wp = W_ih1 + c * kH;
    const f16x8 Aih1_0 = pack_frag(ld4(wp + k0), ld4(wp + 16 + k0));
    wp = W_ih1 + (c + 16) * kH;
    const f16x8 Aih1_1 = pack_frag(ld4(wp + k0), ld4(wp + 16 + k0));

    wp = W_hh1 + c * kH;
    const f16x8 Ahh1_0 = pack_frag(ld4(wp + k0), ld4(wp + 16 + k0));
    wp = W_hh1 + (c + 16) * kH;
    const f16x8 Ahh1_1 = pack_frag(ld4(wp + k0), ld4(wp + 16 + k0));

    // Head: W_ll [4][32] padded to 16 A-rows (rows >=4 zero).
    const f16x8 All = (c < kO)
        ? pack_frag(ld4(W_ll + c * kH + k0), ld4(W_ll + c * kH + 16 + k0))
        : pack_frag(z4, z4);

    // ---- biases as fp32 C-operand fragments (row m = k0+r / 16+k0+r) ----
    f32x4 bias0_0, bias0_1, bias1_0, bias1_1, biasll;
#pragma unroll
    for (int r = 0; r < 4; ++r) {
        bias0_0[r] = b_ih0[k0 + r]      + b_hh0[k0 + r];
        bias0_1[r] = b_ih0[16 + k0 + r] + b_hh0[16 + k0 + r];
        bias1_0[r] = b_ih1[k0 + r]      + b_hh1[k0 + r];
        bias1_1[r] = b_ih1[16 + k0 + r] + b_hh1[16 + k0 + r];
        biasll[r]  = g0 ? b_ll[r] : 0.f;   // head rows >=4 are dead
    }

    // ---- state (B-operand form, H^T), zero initial hidden ----
    union { f16x8 v; uint32_t u[4]; } zz;
    zz.u[0] = zz.u[1] = zz.u[2] = zz.u[3] = 0u;
    f16x8 Bh0 = zz.v, Bh1 = zz.v;

    const float* xp = X   + (size_t)b * (kT * kI);
    float*       op = out + (size_t)b * (kT * kO);

    float4 xv = ld4(xp);   // x_0 (each batch col loaded by its 4 lanes; L1 dedups)

#pragma unroll 4
    for (int t = 0; t < kT; ++t) {
        const int tn = (t + 1 < kT) ? (t + 1) : (kT - 1);
        float4 xnext = ld4(xp + tn * kI);   // prefetch next step

        // x as B-fragment: k=0..3 live only on lane-group 0
        union { f16x8 v; uint32_t u[4]; } bx;
        bx.u[0] = g0 ? __builtin_bit_cast(uint32_t, __builtin_amdgcn_cvt_pkrtz(xv.x, xv.y)) : 0u;
        bx.u[1] = g0 ? __builtin_bit_cast(uint32_t, __builtin_amdgcn_cvt_pkrtz(xv.z, xv.w)) : 0u;
        bx.u[2] = 0u; bx.u[3] = 0u;

        // ---- layer 0: H0' = tanh(W_hh0 H0 + W_ih0 X^T + b0) ----
        f32x4 a0 = MFMA(Ahh0_0, Bh0, bias0_0);
        a0 = MFMA(Aih0_0, bx.v, a0);
        f32x4 a1 = MFMA(Ahh0_1, Bh0, bias0_1);
        a1 = MFMA(Aih0_1, bx.v, a1);

        f32x4 t0, t1;
#pragma unroll
        for (int r = 0; r < 4; ++r) { t0[r] = fast_tanh(a0[r]); t1[r] = fast_tanh(a1[r]); }
        Bh0 = pack_state(t0, t1);

        // ---- layer 1: H1' = tanh(W_ih1 H0' + W_hh1 H1 + b1) ----
        f32x4 c0 = MFMA(Aih1_0, Bh0, bias1_0);
        c0 = MFMA(Ahh1_0, Bh1, c0);
        f32x4 c1 = MFMA(Aih1_1, Bh0, bias1_1);
        c1 = MFMA(Ahh1_1, Bh1, c1);

#pragma unroll
        for (int r = 0; r < 4; ++r) { t0[r] = fast_tanh(c0[r]); t1[r] = fast_tanh(c1[r]); }
        Bh1 = pack_state(t0, t1);

        // ---- head: rows 0-3 of (W_ll_pad H1' + b_ll); lane-group 0 holds them ----
        f32x4 o = MFMA(All, Bh1, biasll);
        if (g0) *(float4*)(op + t * kO) = make_float4(o[0], o[1], o[2], o[3]);

        xv = xnext;
    }
}

extern "C" void kernel_launch(void* const* d_in, const int* in_sizes, int n_in,
                              void* d_out, int out_size, void* d_ws, size_t ws_size,
                              hipStream_t stream) {
    const float* X     = (const float*)d_in[0];
    const float* W_ih0 = (const float*)d_in[1];
    const float* W_hh0 = (const float*)d_in[2];
    const float* b_ih0 = (const float*)d_in[3];
    const float* b_hh0 = (const float*)d_in[4];
    const float* W_ih1 = (const float*)d_in[5];
    const float* W_hh1 = (const float*)d_in[6];
    const float* b_ih1 = (const float*)d_in[7];
    const float* b_hh1 = (const float*)d_in[8];
    const float* W_ll  = (const float*)d_in[9];
    const float* b_ll  = (const float*)d_in[10];
    float* out = (float*)d_out;

    rnn2_mfma<<<dim3(kB / 16), dim3(64), 0, stream>>>(
        X, W_ih0, W_hh0, b_ih0, b_hh0, W_ih1, W_hh1, b_ih1, b_hh1, W_ll, b_ll, out);
}

// Round 3
// 195.889 us; speedup vs baseline: 3.1518x; 1.2784x over previous
//
#include <hip/hip_runtime.h>
#include <cstddef>
#include <cstdint>

// B=8192, T=512, I=4, H=32, O=4 — 2-layer tanh RNN + linear head, fp32 I/O.
constexpr int kB = 8192, kT = 512, kI = 4, kH = 32, kO = 4;

typedef _Float16 f16x8 __attribute__((ext_vector_type(8)));
typedef float    f32x4 __attribute__((ext_vector_type(4)));

#define MFMA(a, b, c) __builtin_amdgcn_mfma_f32_16x16x32_f16((a), (b), (c), 0, 0, 0)

__device__ __forceinline__ float fast_tanh(float x) {
    // tanh(x) = 1 - 2/(e^{2x}+1); exp2-based, saturates correctly, rel err ~1e-6
    float e = __builtin_amdgcn_exp2f(x * 2.8853900817779268f);
    return 1.0f - 2.0f * __builtin_amdgcn_rcpf(e + 1.0f);
}

__device__ __forceinline__ float4 ld4(const float* p) { return *(const float4*)p; }

// A/B fragment from two float4s: elems 0-3 = k {4g..4g+3}, 4-7 = k {16+4g..}.
__device__ __forceinline__ f16x8 pack_frag(float4 lo, float4 hi) {
    f16x8 r;
    r[0] = (_Float16)lo.x; r[1] = (_Float16)lo.y;
    r[2] = (_Float16)lo.z; r[3] = (_Float16)lo.w;
    r[4] = (_Float16)hi.x; r[5] = (_Float16)hi.y;
    r[6] = (_Float16)hi.z; r[7] = (_Float16)hi.w;
    return r;
}

// D-tile regs -> next-step B k-slots; pure per-lane (4x v_cvt_pkrtz).
__device__ __forceinline__ f16x8 pack_state(f32x4 a, f32x4 b) {
    union { f16x8 v; uint32_t u[4]; } r;
    r.u[0] = __builtin_bit_cast(uint32_t, __builtin_amdgcn_cvt_pkrtz(a[0], a[1]));
    r.u[1] = __builtin_bit_cast(uint32_t, __builtin_amdgcn_cvt_pkrtz(a[2], a[3]));
    r.u[2] = __builtin_bit_cast(uint32_t, __builtin_amdgcn_cvt_pkrtz(b[0], b[1]));
    r.u[3] = __builtin_bit_cast(uint32_t, __builtin_amdgcn_cvt_pkrtz(b[2], b[3]));
    return r.v;
}

// One wave per 16-batch tile; state transposed (H^T) so D feeds next B directly.
// Software-pipelined: at iteration t -> L0(step t), L1(step t-1), head(step t-2).
// All 9 MFMAs issue before any result is awaited; tanh stretches overlap MFMA
// latency of the *other* chain. Numerically identical to the unskewed version.
__global__ __launch_bounds__(64, 1) void rnn2_mfma_swp(
    const float* __restrict__ X,
    const float* __restrict__ W_ih0, const float* __restrict__ W_hh0,
    const float* __restrict__ b_ih0, const float* __restrict__ b_hh0,
    const float* __restrict__ W_ih1, const float* __restrict__ W_hh1,
    const float* __restrict__ b_ih1, const float* __restrict__ b_hh1,
    const float* __restrict__ W_ll, const float* __restrict__ b_ll,
    float* __restrict__ out)
{
    const int  l  = threadIdx.x;
    const int  c  = l & 15;          // batch col within tile / A row m
    const int  g  = l >> 4;          // k-group
    const bool g0 = (g == 0);
    const int  b  = blockIdx.x * 16 + c;
    const int  k0 = 4 * g;

    const float4 z4 = make_float4(0.f, 0.f, 0.f, 0.f);

    // ---- weight A-fragments (registers, loop-invariant) ----
    const float* wp;
    wp = W_hh0 + c * kH;
    const f16x8 Ahh0_0 = pack_frag(ld4(wp + k0), ld4(wp + 16 + k0));
    wp = W_hh0 + (c + 16) * kH;
    const f16x8 Ahh0_1 = pack_frag(ld4(wp + k0), ld4(wp + 16 + k0));

    const f16x8 Aih0_0 = pack_frag(g0 ? ld4(W_ih0 + c * kI) : z4, z4);
    const f16x8 Aih0_1 = pack_frag(g0 ? ld4(W_ih0 + (c + 16) * kI) : z4, z4);

    wp = W_ih1 + c * kH;
    const f16x8 Aih1_0 = pack_frag(ld4(wp + k0), ld4(wp + 16 + k0));
    wp = W_ih1 + (c + 16) * kH;
    const f16x8 Aih1_1 = pack_frag(ld4(wp + k0), ld4(wp + 16 + k0));

    wp = W_hh1 + c * kH;
    const f16x8 Ahh1_0 = pack_frag(ld4(wp + k0), ld4(wp + 16 + k0));
    wp = W_hh1 + (c + 16) * kH;
    const f16x8 Ahh1_1 = pack_frag(ld4(wp + k0), ld4(wp + 16 + k0));

    const f16x8 All = (c < kO)
        ? pack_frag(ld4(W_ll + c * kH + k0), ld4(W_ll + c * kH + 16 + k0))
        : pack_frag(z4, z4);

    // ---- biases as C-operand fragments ----
    f32x4 bias0_0, bias0_1, bias1_0, bias1_1, biasll;
#pragma unroll
    for (int r = 0; r < 4; ++r) {
        bias0_0[r] = b_ih0[k0 + r]      + b_hh0[k0 + r];
        bias0_1[r] = b_ih0[16 + k0 + r] + b_hh0[16 + k0 + r];
        bias1_0[r] = b_ih1[k0 + r]      + b_hh1[k0 + r];
        bias1_1[r] = b_ih1[16 + k0 + r] + b_hh1[16 + k0 + r];
        biasll[r]  = g0 ? b_ll[r] : 0.f;
    }

    union { f16x8 v; uint32_t u[4]; } zz;
    zz.u[0] = zz.u[1] = zz.u[2] = zz.u[3] = 0u;
    f16x8 Bh0 = zz.v;   // h0[t-1] at iteration entry
    f16x8 Bh1 = zz.v;   // h1[t-2] at iteration entry

    const float* xp = X   + (size_t)b * (kT * kI);
    float*       op = out + (size_t)b * (kT * kO);

    // ---- prologue: xc[0] = W_ih0·x0 + b0 (off-chain), xn = x[1] ----
    float4 xv = ld4(xp);
    union { f16x8 v; uint32_t u[4]; } bx;
    bx.u[0] = g0 ? __builtin_bit_cast(uint32_t, __builtin_amdgcn_cvt_pkrtz(xv.x, xv.y)) : 0u;
    bx.u[1] = g0 ? __builtin_bit_cast(uint32_t, __builtin_amdgcn_cvt_pkrtz(xv.z, xv.w)) : 0u;
    bx.u[2] = 0u; bx.u[3] = 0u;
    f32x4 xc0 = MFMA(Aih0_0, bx.v, bias0_0);
    f32x4 xc1 = MFMA(Aih0_1, bx.v, bias0_1);
    float4 xn = ld4(xp + kI);

#pragma unroll 2
    for (int t = 0; t < kT + 2; ++t) {
        // (1) L0, step t: a = W_hh0·h0[t-1] + xc[t]     (1 chained MFMA)
        f32x4 a0 = MFMA(Ahh0_0, Bh0, xc0);
        f32x4 a1 = MFMA(Ahh0_1, Bh0, xc1);
        // (2) L1, step t-1: c = W_ih1·h0[t-1] + W_hh1·h1[t-2] + b1
        f32x4 c0 = MFMA(Aih1_0, Bh0, bias1_0);
        f32x4 c1 = MFMA(Aih1_1, Bh0, bias1_1);
        c0 = MFMA(Ahh1_0, Bh1, c0);
        c1 = MFMA(Ahh1_1, Bh1, c1);
        // (3) head, step t-2: o = W_ll·h1[t-2] + b_ll
        f32x4 o = MFMA(All, Bh1, biasll);
        // (4) xc for step t+1 (off-chain)
        union { f16x8 v; uint32_t u[4]; } bx2;
        bx2.u[0] = g0 ? __builtin_bit_cast(uint32_t, __builtin_amdgcn_cvt_pkrtz(xn.x, xn.y)) : 0u;
        bx2.u[1] = g0 ? __builtin_bit_cast(uint32_t, __builtin_amdgcn_cvt_pkrtz(xn.z, xn.w)) : 0u;
        bx2.u[2] = 0u; bx2.u[3] = 0u;
        f32x4 xc0n = MFMA(Aih0_0, bx2.v, bias0_0);
        f32x4 xc1n = MFMA(Aih0_1, bx2.v, bias0_1);
        // (5) prefetch x[t+2] (clamped; garbage only feeds never-stored steps)
        const int tl = (t + 2 < kT) ? (t + 2) : (kT - 1);
        float4 xn2 = ld4(xp + tl * kI);

        // (6) finish L0: h0[t]
        f32x4 t0, t1;
#pragma unroll
        for (int r = 0; r < 4; ++r) { t0[r] = fast_tanh(a0[r]); t1[r] = fast_tanh(a1[r]); }
        Bh0 = pack_state(t0, t1);

        // (7) finish L1: h1[t-1]  (t=0 computes bogus h1[-1]; force to 0)
        f32x4 u0, u1;
#pragma unroll
        for (int r = 0; r < 4; ++r) { u0[r] = fast_tanh(c0[r]); u1[r] = fast_tanh(c1[r]); }
        Bh1 = pack_state(u0, u1);
        if (t == 0) Bh1 = zz.v;

        // (8) store head result for step t-2
        if (t >= 2 && g0)
            *(float4*)(op + (t - 2) * kO) = make_float4(o[0], o[1], o[2], o[3]);

        xc0 = xc0n; xc1 = xc1n; xn = xn2;
    }
}

extern "C" void kernel_launch(void* const* d_in, const int* in_sizes, int n_in,
                              void* d_out, int out_size, void* d_ws, size_t ws_size,
                              hipStream_t stream) {
    const float* X     = (const float*)d_in[0];
    const float* W_ih0 = (const float*)d_in[1];
    const float* W_hh0 = (const float*)d_in[2];
    const float* b_ih0 = (const float*)d_in[3];
    const float* b_hh0 = (const float*)d_in[4];
    const float* W_ih1 = (const float*)d_in[5];
    const float* W_hh1 = (const float*)d_in[6];
    const float* b_ih1 = (const float*)d_in[7];
    const float* b_hh1 = (const float*)d_in[8];
    const float* W_ll  = (const float*)d_in[9];
    const float* b_ll  = (const float*)d_in[10];
    float* out = (float*)d_out;

    rnn2_mfma_swp<<<dim3(kB / 16), dim3(64), 0, stream>>>(
        X, W_ih0, W_hh0, b_ih0, b_hh0, W_ih1, W_hh1, b_ih1, b_hh1, W_ll, b_ll, out);
}

// Round 5
// 181.666 us; speedup vs baseline: 3.3985x; 1.0783x over previous
//
#include <hip/hip_runtime.h>
#include <cstddef>
#include <cstdint>

// B=8192, T=512, I=4, H=32, O=4 — 2-layer tanh RNN + linear head, fp32 I/O.
constexpr int kB = 8192, kT = 512, kI = 4, kH = 32, kO = 4;

typedef _Float16 f16x8 __attribute__((ext_vector_type(8)));
typedef float    f32x4 __attribute__((ext_vector_type(4)));

#define MFMA(a, b, c) __builtin_amdgcn_mfma_f32_16x16x32_f16((a), (b), (c), 0, 0, 0)

__device__ __forceinline__ float fast_tanh(float x) {
    // tanh(x) = 1 - 2/(e^{2x}+1); exp2-based, saturates correctly, rel err ~1e-6
    float e = __builtin_amdgcn_exp2f(x * 2.8853900817779268f);
    return 1.0f - 2.0f * __builtin_amdgcn_rcpf(e + 1.0f);
}

__device__ __forceinline__ float4 ld4(const float* p) { return *(const float4*)p; }

// A/B fragment from two float4s: elems 0-3 = k {4g..4g+3}, 4-7 = k {16+4g..}.
__device__ __forceinline__ f16x8 pack_frag(float4 lo, float4 hi) {
    f16x8 r;
    r[0] = (_Float16)lo.x; r[1] = (_Float16)lo.y;
    r[2] = (_Float16)lo.z; r[3] = (_Float16)lo.w;
    r[4] = (_Float16)hi.x; r[5] = (_Float16)hi.y;
    r[6] = (_Float16)hi.z; r[7] = (_Float16)hi.w;
    return r;
}

// D-tile regs -> next-step B k-slots; pure per-lane (4x v_cvt_pkrtz).
__device__ __forceinline__ f16x8 pack_state(f32x4 a, f32x4 b) {
    union { f16x8 v; uint32_t u[4]; } r;
    r.u[0] = __builtin_bit_cast(uint32_t, __builtin_amdgcn_cvt_pkrtz(a[0], a[1]));
    r.u[1] = __builtin_bit_cast(uint32_t, __builtin_amdgcn_cvt_pkrtz(a[2], a[3]));
    r.u[2] = __builtin_bit_cast(uint32_t, __builtin_amdgcn_cvt_pkrtz(b[0], b[1]));
    r.u[3] = __builtin_bit_cast(uint32_t, __builtin_amdgcn_cvt_pkrtz(b[2], b[3]));
    return r.v;
}

// One wave per 16-batch tile; state transposed (H^T) so D feeds next B directly.
// Pipelined: iteration t computes L0(t), L1(t-1), head(t-2). Time loop blocked
// by 4 with double-buffered x loads (>=4 iterations of slack, ~1600 cy — covers
// an HBM miss); next-block loads issue BEFORE this block's stores so load waits
// never drain stores.
__global__ __launch_bounds__(64, 1) void rnn2_mfma_swp4(
    const float* __restrict__ X,
    const float* __restrict__ W_ih0, const float* __restrict__ W_hh0,
    const float* __restrict__ b_ih0, const float* __restrict__ b_hh0,
    const float* __restrict__ W_ih1, const float* __restrict__ W_hh1,
    const float* __restrict__ b_ih1, const float* __restrict__ b_hh1,
    const float* __restrict__ W_ll, const float* __restrict__ b_ll,
    float* __restrict__ out)
{
    const int  l  = threadIdx.x;
    const int  c  = l & 15;          // batch col within tile / A row m
    const int  g  = l >> 4;          // k-group
    const bool g0 = (g == 0);
    const int  b  = blockIdx.x * 16 + c;
    const int  k0 = 4 * g;

    const float4 z4 = make_float4(0.f, 0.f, 0.f, 0.f);

    // ---- weight A-fragments (registers, loop-invariant) ----
    const float* wp;
    wp = W_hh0 + c * kH;
    const f16x8 Ahh0_0 = pack_frag(ld4(wp + k0), ld4(wp + 16 + k0));
    wp = W_hh0 + (c + 16) * kH;
    const f16x8 Ahh0_1 = pack_frag(ld4(wp + k0), ld4(wp + 16 + k0));

    const f16x8 Aih0_0 = pack_frag(g0 ? ld4(W_ih0 + c * kI) : z4, z4);
    const f16x8 Aih0_1 = pack_frag(g0 ? ld4(W_ih0 + (c + 16) * kI) : z4, z4);

    wp = W_ih1 + c * kH;
    const f16x8 Aih1_0 = pack_frag(ld4(wp + k0), ld4(wp + 16 + k0));
    wp = W_ih1 + (c + 16) * kH;
    const f16x8 Aih1_1 = pack_frag(ld4(wp + k0), ld4(wp + 16 + k0));

    wp = W_hh1 + c * kH;
    const f16x8 Ahh1_0 = pack_frag(ld4(wp + k0), ld4(wp + 16 + k0));
    wp = W_hh1 + (c + 16) * kH;
    const f16x8 Ahh1_1 = pack_frag(ld4(wp + k0), ld4(wp + 16 + k0));

    const f16x8 All = (c < kO)
        ? pack_frag(ld4(W_ll + c * kH + k0), ld4(W_ll + c * kH + 16 + k0))
        : pack_frag(z4, z4);

    // ---- biases as C-operand fragments ----
    f32x4 bias0_0, bias0_1, bias1_0, bias1_1, biasll;
#pragma unroll
    for (int r = 0; r < 4; ++r) {
        bias0_0[r] = b_ih0[k0 + r]      + b_hh0[k0 + r];
        bias0_1[r] = b_ih0[16 + k0 + r] + b_hh0[16 + k0 + r];
        bias1_0[r] = b_ih1[k0 + r]      + b_hh1[k0 + r];
        bias1_1[r] = b_ih1[16 + k0 + r] + b_hh1[16 + k0 + r];
        biasll[r]  = g0 ? b_ll[r] : 0.f;
    }

    union { f16x8 v; uint32_t u[4]; } zz;
    zz.u[0] = zz.u[1] = zz.u[2] = zz.u[3] = 0u;
    f16x8 Bh0 = zz.v;   // h0[t-1] at iteration entry
    f16x8 Bh1 = zz.v;   // h1[t-2] at iteration entry
    f32x4 xc0, xc1;     // xc[t] = W_ih0·x[t] + b0, in D layout

    const float* xp = X   + (size_t)b * (kT * kI);
    float*       op = out + (size_t)b * (kT * kO);

    // One pipeline iteration. xn = x[t+1]; sp = output row for step t-2 (or null).
    auto step = [&](float4 xn, float* sp) {
        // x-pack first (independent VALU) so all 9 MFMAs can issue back-to-back
        union { f16x8 v; uint32_t u[4]; } bx;
        bx.u[0] = g0 ? __builtin_bit_cast(uint32_t, __builtin_amdgcn_cvt_pkrtz(xn.x, xn.y)) : 0u;
        bx.u[1] = g0 ? __builtin_bit_cast(uint32_t, __builtin_amdgcn_cvt_pkrtz(xn.z, xn.w)) : 0u;
        bx.u[2] = 0u; bx.u[3] = 0u;

        // L0 (step t), L1 (step t-1), head (step t-2), xc (step t+1)
        f32x4 a0 = MFMA(Ahh0_0, Bh0, xc0);
        f32x4 a1 = MFMA(Ahh0_1, Bh0, xc1);
        f32x4 c0 = MFMA(Aih1_0, Bh0, bias1_0);
        f32x4 c1 = MFMA(Aih1_1, Bh0, bias1_1);
        c0 = MFMA(Ahh1_0, Bh1, c0);
        c1 = MFMA(Ahh1_1, Bh1, c1);
        f32x4 o = MFMA(All, Bh1, biasll);
        xc0 = MFMA(Aih0_0, bx.v, bias0_0);
        xc1 = MFMA(Aih0_1, bx.v, bias0_1);

        f32x4 t0, t1;
#pragma unroll
        for (int r = 0; r < 4; ++r) { t0[r] = fast_tanh(a0[r]); t1[r] = fast_tanh(a1[r]); }
        Bh0 = pack_state(t0, t1);

        f32x4 u0, u1;
#pragma unroll
        for (int r = 0; r < 4; ++r) { u0[r] = fast_tanh(c0[r]); u1[r] = fast_tanh(c1[r]); }
        Bh1 = pack_state(u0, u1);

        if (sp && g0) *(float4*)sp = make_float4(o[0], o[1], o[2], o[3]);
    };

    // ---- prologue: load x[0..2] and first block's x[3..6]; xc[0]; t=0,1 ----
    float4 xv0 = ld4(xp);
    float4 xv1 = ld4(xp + 1 * kI);
    float4 xv2 = ld4(xp + 2 * kI);
    float4 xcur[4];
#pragma unroll
    for (int u = 0; u < 4; ++u) xcur[u] = ld4(xp + (3 + u) * kI);

    {
        union { f16x8 v; uint32_t u[4]; } bx;
        bx.u[0] = g0 ? __builtin_bit_cast(uint32_t, __builtin_amdgcn_cvt_pkrtz(xv0.x, xv0.y)) : 0u;
        bx.u[1] = g0 ? __builtin_bit_cast(uint32_t, __builtin_amdgcn_cvt_pkrtz(xv0.z, xv0.w)) : 0u;
        bx.u[2] = 0u; bx.u[3] = 0u;
        xc0 = MFMA(Aih0_0, bx.v, bias0_0);
        xc1 = MFMA(Aih0_1, bx.v, bias0_1);
    }
    step(xv1, nullptr);          // t = 0
    Bh1 = zz.v;                  // h1[-1] = 0
    step(xv2, nullptr);          // t = 1

    // ---- main loop: t = 2 .. 513 in 128 blocks of 4; all iterations store ----
    for (int tb = 0; tb < kT / 4; ++tb) {
        const int t0b = 2 + tb * 4;
        // issue next block's x loads first (never gated by this block's stores)
        float4 xnxt[4];
#pragma unroll
        for (int u = 0; u < 4; ++u) {
            int idx = t0b + 5 + u;
            idx = idx < kT ? idx : (kT - 1);
            xnxt[u] = ld4(xp + idx * kI);
        }
#pragma unroll
        for (int u = 0; u < 4; ++u)
            step(xcur[u], op + (size_t)(t0b + u - 2) * kO);
#pragma unroll
        for (int u = 0; u < 4; ++u) xcur[u] = xnxt[u];
    }
}

extern "C" void kernel_launch(void* const* d_in, const int* in_sizes, int n_in,
                              void* d_out, int out_size, void* d_ws, size_t ws_size,
                              hipStream_t stream) {
    const float* X     = (const float*)d_in[0];
    const float* W_ih0 = (const float*)d_in[1];
    const float* W_hh0 = (const float*)d_in[2];
    const float* b_ih0 = (const float*)d_in[3];
    const float* b_hh0 = (const float*)d_in[4];
    const float* W_ih1 = (const float*)d_in[5];
    const float* W_hh1 = (const float*)d_in[6];
    const float* b_ih1 = (const float*)d_in[7];
    const float* b_hh1 = (const float*)d_in[8];
    const float* W_ll  = (const float*)d_in[9];
    const float* b_ll  = (const float*)d_in[10];
    float* out = (float*)d_out;

    rnn2_mfma_swp4<<<dim3(kB / 16), dim3(64), 0, stream>>>(
        X, W_ih0, W_hh0, b_ih0, b_hh0, W_ih1, W_hh1, b_ih1, b_hh1, W_ll, b_ll, out);
}

// Round 6
// 169.730 us; speedup vs baseline: 3.6375x; 1.0703x over previous
//
#include <hip/hip_runtime.h>
#include <cstddef>
#include <cstdint>

// B=8192, T=512, I=4, H=32, O=4 — 2-layer tanh RNN + linear head, fp32 I/O.
constexpr int kB = 8192, kT = 512, kI = 4, kH = 32, kO = 4;

typedef _Float16 f16x8 __attribute__((ext_vector_type(8)));
typedef float    f32x4 __attribute__((ext_vector_type(4)));

#define MFMA(a, b, c) __builtin_amdgcn_mfma_f32_16x16x32_f16((a), (b), (c), 0, 0, 0)

__device__ __forceinline__ float fast_tanh(float x) {
    // tanh(x) = 1 - 2/(e^{2x}+1); exp2-based, saturates correctly, rel err ~1e-6
    float e = __builtin_amdgcn_exp2f(x * 2.8853900817779268f);
    return 1.0f - 2.0f * __builtin_amdgcn_rcpf(e + 1.0f);
}

__device__ __forceinline__ float4 ld4(const float* p) { return *(const float4*)p; }

// A/B fragment from two float4s: elems 0-3 = k {4g..4g+3}, 4-7 = k {16+4g..}.
__device__ __forceinline__ f16x8 pack_frag(float4 lo, float4 hi) {
    f16x8 r;
    r[0] = (_Float16)lo.x; r[1] = (_Float16)lo.y;
    r[2] = (_Float16)lo.z; r[3] = (_Float16)lo.w;
    r[4] = (_Float16)hi.x; r[5] = (_Float16)hi.y;
    r[6] = (_Float16)hi.z; r[7] = (_Float16)hi.w;
    return r;
}

// D-tile regs -> next-step B k-slots; pure per-lane (4x v_cvt_pkrtz).
__device__ __forceinline__ f16x8 pack_state(f32x4 a, f32x4 b) {
    union { f16x8 v; uint32_t u[4]; } r;
    r.u[0] = __builtin_bit_cast(uint32_t, __builtin_amdgcn_cvt_pkrtz(a[0], a[1]));
    r.u[1] = __builtin_bit_cast(uint32_t, __builtin_amdgcn_cvt_pkrtz(a[2], a[3]));
    r.u[2] = __builtin_bit_cast(uint32_t, __builtin_amdgcn_cvt_pkrtz(b[0], b[1]));
    r.u[3] = __builtin_bit_cast(uint32_t, __builtin_amdgcn_cvt_pkrtz(b[2], b[3]));
    return r.v;
}

// Producer/consumer split: wave 0 = layer 0, wave 1 = layer 1 + head.
// h0 fragments cross via double-buffered LDS (lane-aligned, bit-identical f16);
// one barrier per step; L1 runs one step behind L0 so the handoff has slack.
// 1024 waves total -> one per SIMD on all 1024 SIMDs (vs 512 before).
__global__ __launch_bounds__(128, 1) void rnn2_split(
    const float* __restrict__ X,
    const float* __restrict__ W_ih0, const float* __restrict__ W_hh0,
    const float* __restrict__ b_ih0, const float* __restrict__ b_hh0,
    const float* __restrict__ W_ih1, const float* __restrict__ W_hh1,
    const float* __restrict__ b_ih1, const float* __restrict__ b_hh1,
    const float* __restrict__ W_ll, const float* __restrict__ b_ll,
    float* __restrict__ out)
{
    const int  tid = threadIdx.x;
    const int  wid = tid >> 6;       // 0 = L0 producer, 1 = L1+head consumer
    const int  l   = tid & 63;
    const int  c   = l & 15;         // batch col within tile / A row m
    const int  g   = l >> 4;         // k-group
    const bool g0  = (g == 0);
    const int  b   = blockIdx.x * 16 + c;
    const int  k0  = 4 * g;

    __shared__ uint4 h0buf[2][64];   // double-buffered h0 B-fragments

    const float4 z4 = make_float4(0.f, 0.f, 0.f, 0.f);
    union { f16x8 v; uint32_t u[4]; } zz;
    zz.u[0] = zz.u[1] = zz.u[2] = zz.u[3] = 0u;

    if (wid == 0) {
        // ================= producer: layer 0 =================
        const float* wp = W_hh0 + c * kH;
        const f16x8 Ahh0_0 = pack_frag(ld4(wp + k0), ld4(wp + 16 + k0));
        wp = W_hh0 + (c + 16) * kH;
        const f16x8 Ahh0_1 = pack_frag(ld4(wp + k0), ld4(wp + 16 + k0));
        const f16x8 Aih0_0 = pack_frag(g0 ? ld4(W_ih0 + c * kI) : z4, z4);
        const f16x8 Aih0_1 = pack_frag(g0 ? ld4(W_ih0 + (c + 16) * kI) : z4, z4);

        f32x4 bias0_0, bias0_1;
#pragma unroll
        for (int r = 0; r < 4; ++r) {
            bias0_0[r] = b_ih0[k0 + r]      + b_hh0[k0 + r];
            bias0_1[r] = b_ih0[16 + k0 + r] + b_hh0[16 + k0 + r];
        }

        f16x8 Bh0 = zz.v;
        f32x4 xc0, xc1;
        const float* xp = X + (size_t)b * (kT * kI);

        float4 xv0 = ld4(xp);
        float4 xv1 = ld4(xp + 1 * kI);
        float4 xv2 = ld4(xp + 2 * kI);
        float4 xcur[4];
#pragma unroll
        for (int u = 0; u < 4; ++u) xcur[u] = ld4(xp + (3 + u) * kI);

        {   // xc[0] = W_ih0·x0 + b0
            union { f16x8 v; uint32_t u[4]; } bx;
            bx.u[0] = g0 ? __builtin_bit_cast(uint32_t, __builtin_amdgcn_cvt_pkrtz(xv0.x, xv0.y)) : 0u;
            bx.u[1] = g0 ? __builtin_bit_cast(uint32_t, __builtin_amdgcn_cvt_pkrtz(xv0.z, xv0.w)) : 0u;
            bx.u[2] = 0u; bx.u[3] = 0u;
            xc0 = MFMA(Aih0_0, bx.v, bias0_0);
            xc1 = MFMA(Aih0_1, bx.v, bias0_1);
        }

        // One L0 iteration: consumes Bh0 (h0[i-1]), xc[i]; produces h0[i] into
        // h0buf[par]; prepares xc[i+1] from xn = x[i+1].
        auto stepA = [&](float4 xn, int par) {
            union { f16x8 v; uint32_t u[4]; } bx;
            bx.u[0] = g0 ? __builtin_bit_cast(uint32_t, __builtin_amdgcn_cvt_pkrtz(xn.x, xn.y)) : 0u;
            bx.u[1] = g0 ? __builtin_bit_cast(uint32_t, __builtin_amdgcn_cvt_pkrtz(xn.z, xn.w)) : 0u;
            bx.u[2] = 0u; bx.u[3] = 0u;

            f32x4 a0 = MFMA(Ahh0_0, Bh0, xc0);
            f32x4 a1 = MFMA(Ahh0_1, Bh0, xc1);
            xc0 = MFMA(Aih0_0, bx.v, bias0_0);
            xc1 = MFMA(Aih0_1, bx.v, bias0_1);

            f32x4 t0, t1;
#pragma unroll
            for (int r = 0; r < 4; ++r) { t0[r] = fast_tanh(a0[r]); t1[r] = fast_tanh(a1[r]); }
            Bh0 = pack_state(t0, t1);
            h0buf[par][l] = __builtin_bit_cast(uint4, Bh0);
        };

        stepA(xv1, 0); __syncthreads();   // i = 0
        stepA(xv2, 1); __syncthreads();   // i = 1

        for (int tb = 0; tb < kT / 4; ++tb) {
            const int t0b = 2 + tb * 4;
            float4 xnxt[4];
#pragma unroll
            for (int u = 0; u < 4; ++u) {
                int idx = t0b + 5 + u;
                idx = idx < kT ? idx : (kT - 1);
                xnxt[u] = ld4(xp + idx * kI);
            }
            stepA(xcur[0], 0); __syncthreads();
            stepA(xcur[1], 1); __syncthreads();
            stepA(xcur[2], 0); __syncthreads();
            stepA(xcur[3], 1); __syncthreads();
#pragma unroll
            for (int u = 0; u < 4; ++u) xcur[u] = xnxt[u];
        }
    } else {
        // ================= consumer: layer 1 + head =================
        const float* wp = W_ih1 + c * kH;
        const f16x8 Aih1_0 = pack_frag(ld4(wp + k0), ld4(wp + 16 + k0));
        wp = W_ih1 + (c + 16) * kH;
        const f16x8 Aih1_1 = pack_frag(ld4(wp + k0), ld4(wp + 16 + k0));
        wp = W_hh1 + c * kH;
        const f16x8 Ahh1_0 = pack_frag(ld4(wp + k0), ld4(wp + 16 + k0));
        wp = W_hh1 + (c + 16) * kH;
        const f16x8 Ahh1_1 = pack_frag(ld4(wp + k0), ld4(wp + 16 + k0));
        const f16x8 All = (c < kO)
            ? pack_frag(ld4(W_ll + c * kH + k0), ld4(W_ll + c * kH + 16 + k0))
            : pack_frag(z4, z4);

        f32x4 bias1_0, bias1_1, biasll;
#pragma unroll
        for (int r = 0; r < 4; ++r) {
            bias1_0[r] = b_ih1[k0 + r]      + b_hh1[k0 + r];
            bias1_1[r] = b_ih1[16 + k0 + r] + b_hh1[16 + k0 + r];
            biasll[r]  = g0 ? b_ll[r] : 0.f;
        }

        f16x8 Bh1 = zz.v;   // h1[i-2] at iteration entry
        float* op = out + (size_t)b * (kT * kO);

        // One L1 iteration at pipeline index i: head emits step i-2 from Bh1;
        // consumes h0[i-1] from h0buf[par]; produces h1[i-1].
        auto stepB = [&](int par, float* sp) {
            const f16x8 Bh0p = __builtin_bit_cast(f16x8, h0buf[par][l]);
            f32x4 o  = MFMA(All, Bh1, biasll);          // head, step i-2
            f32x4 c0 = MFMA(Aih1_0, Bh0p, bias1_0);
            f32x4 c1 = MFMA(Aih1_1, Bh0p, bias1_1);
            c0 = MFMA(Ahh1_0, Bh1, c0);
            c1 = MFMA(Ahh1_1, Bh1, c1);

            f32x4 u0, u1;
#pragma unroll
            for (int r = 0; r < 4; ++r) { u0[r] = fast_tanh(c0[r]); u1[r] = fast_tanh(c1[r]); }
            Bh1 = pack_state(u0, u1);
            if (sp && g0) *(float4*)sp = make_float4(o[0], o[1], o[2], o[3]);
        };

        stepB(1, nullptr);   // i = 0: reads uninit buf[1] -> result discarded
        Bh1 = zz.v;          // enforce h1[-1] = 0
        __syncthreads();
        stepB(0, nullptr);   // i = 1: h0[0] -> h1[0]
        __syncthreads();

        for (int tb = 0; tb < kT / 4; ++tb) {
            const int t0b = 2 + tb * 4;
            stepB(1, op + (size_t)(t0b - 2) * kO); __syncthreads();
            stepB(0, op + (size_t)(t0b - 1) * kO); __syncthreads();
            stepB(1, op + (size_t)(t0b + 0) * kO); __syncthreads();
            stepB(0, op + (size_t)(t0b + 1) * kO); __syncthreads();
        }
    }
}

extern "C" void kernel_launch(void* const* d_in, const int* in_sizes, int n_in,
                              void* d_out, int out_size, void* d_ws, size_t ws_size,
                              hipStream_t stream) {
    const float* X     = (const float*)d_in[0];
    const float* W_ih0 = (const float*)d_in[1];
    const float* W_hh0 = (const float*)d_in[2];
    const float* b_ih0 = (const float*)d_in[3];
    const float* b_hh0 = (const float*)d_in[4];
    const float* W_ih1 = (const float*)d_in[5];
    const float* W_hh1 = (const float*)d_in[6];
    const float* b_ih1 = (const float*)d_in[7];
    const float* b_hh1 = (const float*)d_in[8];
    const float* W_ll  = (const float*)d_in[9];
    const float* b_ll  = (const float*)d_in[10];
    float* out = (float*)d_out;

    rnn2_split<<<dim3(kB / 16), dim3(128), 0, stream>>>(
        X, W_ih0, W_hh0, b_ih0, b_hh0, W_ih1, W_hh1, b_ih1, b_hh1, W_ll, b_ll, out);
}